// Round 4
// baseline (344.187 us; speedup 1.0000x reference)
//
#include <hip/hip_runtime.h>
#include <math.h>

namespace {

constexpr int Bn = 4, Cn = 96, Hn = 64, Wn = 64, Ln = 4096, Din = 192;
constexpr int Kn = 4, Rn = 6, Dmlp = 384;
constexpr int NCH = 128, CLEN = 32;   // 128 chunks * 32 = L

__device__ __forceinline__ float softplusf_(float x) {
  return fmaxf(x, 0.f) + log1pf(expf(-fabsf(x)));
}
__device__ __forceinline__ float siluf_(float x) { return x / (1.f + expf(-x)); }
__device__ __forceinline__ float geluf_(float x) {
  return 0.5f * x * (1.f + erff(x * 0.7071067811865476f));
}

// ---------------------------------------------------------------------------
// K1: LayerNorm(96) + in_proj (96->192). 16 px/block, 256 thr, grid 1024.
// ---------------------------------------------------------------------------
__global__ __launch_bounds__(256) void k1_ln_inproj(
    const float* __restrict__ x, const float* __restrict__ gam,
    const float* __restrict__ bet, const float* __restrict__ W,
    float* __restrict__ ucp) {
  __shared__ float sx[16 * 97];
  const int tid = threadIdx.x;
  const int p0 = blockIdx.x * 16;
  const int b = p0 >> 12, pl0 = p0 & (Ln - 1);

  for (int f = tid; f < 16 * 96; f += 256) {
    int c = f >> 4, pp = f & 15;
    sx[pp * 97 + c] = x[((size_t)b * Cn + c) * Ln + pl0 + pp];
  }
  __syncthreads();
  {
    const int pp = tid >> 4, t16 = tid & 15;  // 16 lanes/px, 6 ch each
    float s = 0.f;
    for (int c = t16 * 6; c < t16 * 6 + 6; ++c) s += sx[pp * 97 + c];
    s += __shfl_xor(s, 1, 16); s += __shfl_xor(s, 2, 16);
    s += __shfl_xor(s, 4, 16); s += __shfl_xor(s, 8, 16);
    float m = s * (1.f / 96.f);
    float v = 0.f;
    for (int c = t16 * 6; c < t16 * 6 + 6; ++c) {
      float t = sx[pp * 97 + c] - m; v += t * t;
    }
    v += __shfl_xor(v, 1, 16); v += __shfl_xor(v, 2, 16);
    v += __shfl_xor(v, 4, 16); v += __shfl_xor(v, 8, 16);
    float rs = rsqrtf(v * (1.f / 96.f) + 1e-5f);
    for (int c = t16 * 6; c < t16 * 6 + 6; ++c)
      sx[pp * 97 + c] = (sx[pp * 97 + c] - m) * rs * gam[c] + bet[c];
  }
  __syncthreads();

  // GEMM 16px x 192j: g=tid&3 -> 4 px, q=tid>>2 (0..63) -> 3 j's
  const int g = tid & 3, q = tid >> 2;
  float acc[4][3];
#pragma unroll
  for (int i = 0; i < 4; ++i)
#pragma unroll
    for (int j = 0; j < 3; ++j) acc[i][j] = 0.f;

  for (int c = 0; c < 96; ++c) {
    float xv[4];
#pragma unroll
    for (int i = 0; i < 4; ++i) xv[i] = sx[(4 * g + i) * 97 + c];
#pragma unroll
    for (int j = 0; j < 3; ++j) {
      float wv = W[(q * 3 + j) * 96 + c];
#pragma unroll
      for (int i = 0; i < 4; ++i) acc[i][j] = fmaf(xv[i], wv, acc[i][j]);
    }
  }
#pragma unroll
  for (int j = 0; j < 3; ++j) {
    int jj = q * 3 + j;
    float4 v = make_float4(acc[0][j], acc[1][j], acc[2][j], acc[3][j]);
    *reinterpret_cast<float4*>(
        &ucp[((size_t)b * Din + jj) * Ln + pl0 + 4 * g]) = v;
  }
}

// ---------------------------------------------------------------------------
// K2: depthwise 3x3 conv + SiLU -> ut + fused x_proj -> dblp. 512 threads.
// ---------------------------------------------------------------------------
__global__ __launch_bounds__(512) void k2_conv_proj(
    const float* __restrict__ ucp, const float* __restrict__ cw,
    const float* __restrict__ xw, float* __restrict__ ut,
    float* __restrict__ dblp) {
  __shared__ float su[64 * 193];
  const int tid = threadIdx.x;
  const int bh = blockIdx.x;
  const int b = bh >> 6, h = bh & 63;
  const int w = tid & 63, wg = tid >> 6;   // 8 groups x 24 ch

  for (int dd = 0; dd < 24; ++dd) {
    int d = wg * 24 + dd;
    const float* base = &ucp[((size_t)b * Din + d) * Ln];
    float r0 = (h > 0) ? base[(h - 1) * 64 + w] : 0.f;
    float r1 = base[h * 64 + w];
    float r2 = (h < 63) ? base[(h + 1) * 64 + w] : 0.f;
    const float* wt = &cw[d * 9];
    float rl, rr, acc;
    rl = __shfl(r0, (w + 63) & 63); if (w == 0) rl = 0.f;
    rr = __shfl(r0, (w + 1) & 63);  if (w == 63) rr = 0.f;
    acc = rl * wt[0] + r0 * wt[1] + rr * wt[2];
    rl = __shfl(r1, (w + 63) & 63); if (w == 0) rl = 0.f;
    rr = __shfl(r1, (w + 1) & 63);  if (w == 63) rr = 0.f;
    acc += rl * wt[3] + r1 * wt[4] + rr * wt[5];
    rl = __shfl(r2, (w + 63) & 63); if (w == 0) rl = 0.f;
    rr = __shfl(r2, (w + 1) & 63);  if (w == 63) rr = 0.f;
    acc += rl * wt[6] + r2 * wt[7] + rr * wt[8];
    su[w * 193 + d] = siluf_(acc);
  }
  __syncthreads();

  for (int f = tid; f < 64 * Din; f += 512) {
    int pp = f / Din, d = f % Din;
    ut[((size_t)b * Ln + h * 64 + pp) * Din + d] = su[pp * 193 + d];
  }

  // x_proj: w2 = tid>>3 -> pixel, 8 lanes/px: k=lane>>1, half jh=lane&1
  const int w2 = tid >> 3, j8 = tid & 7;
  const int k = j8 >> 1, jh = j8 & 1;
  float a4[4];
#pragma unroll
  for (int j = 0; j < 4; ++j) a4[j] = 0.f;
  for (int d = 0; d < Din; ++d) {
    float uv = su[w2 * 193 + d];
#pragma unroll
    for (int j = 0; j < 4; ++j)
      a4[j] = fmaf(uv, xw[(k * 8 + jh * 4 + j) * Din + d], a4[j]);
  }
  float4 v4 = make_float4(a4[0], a4[1], a4[2], a4[3]);
  *reinterpret_cast<float4*>(
      &dblp[((size_t)b * Ln + h * 64 + w2) * 32 + k * 8 + jh * 4]) = v4;
}

__device__ __forceinline__ int scan_pixel(int k, int l) {
  if (k == 0) return l;
  if (k == 1) return ((l & 63) << 6) | (l >> 6);
  if (k == 2) return Ln - 1 - l;
  int m2 = Ln - 1 - l;
  return ((m2 & 63) << 6) | (m2 >> 6);
}

// ---------------------------------------------------------------------------
// K4: scan pass 1
// ---------------------------------------------------------------------------
__global__ __launch_bounds__(192) void k4_scan1(
    const float* __restrict__ ut, const float* __restrict__ dblp,
    const float* __restrict__ wdtg, const float* __restrict__ bdtg,
    const float* __restrict__ alog, float* __restrict__ apb,
    float* __restrict__ heb) {
  const int bid = blockIdx.x;
  const int ch = bid & (NCH - 1);
  const int bk = bid / NCH;
  const int b = bk >> 2, k = bk & 3;
  const int d = threadIdx.x;

  float wdt[6];
#pragma unroll
  for (int r = 0; r < 6; ++r) wdt[r] = wdtg[(k * Din + d) * 6 + r];
  const float bdt = bdtg[k * Din + d];
  const float Av = -expf(alog[k * Din + d]);

  const float* utb = &ut[(size_t)b * Ln * Din];
  const float* dbb = &dblp[(size_t)b * Ln * 32 + k * 8];

  float h = 0.f, ap = 1.f;
  for (int i = 0; i < CLEN; ++i) {
    int l = ch * CLEN + i;
    int p = scan_pixel(k, l);
    const float* dl = &dbb[(size_t)p * 32];
    float4 q0 = *reinterpret_cast<const float4*>(dl);
    float4 q1 = *reinterpret_cast<const float4*>(dl + 4);
    float xdt = bdt;
    xdt = fmaf(q0.x, wdt[0], xdt); xdt = fmaf(q0.y, wdt[1], xdt);
    xdt = fmaf(q0.z, wdt[2], xdt); xdt = fmaf(q0.w, wdt[3], xdt);
    xdt = fmaf(q1.x, wdt[4], xdt); xdt = fmaf(q1.y, wdt[5], xdt);
    float dt = softplusf_(xdt);
    float bs = q1.z;
    float u = utb[(size_t)p * Din + d];
    float a = expf(dt * Av);
    float bbv = dt * bs * u;
    h = fmaf(a, h, bbv);
    ap *= a;
  }
  size_t o = ((size_t)bk * NCH + ch) * Din + d;
  apb[o] = ap;
  heb[o] = h;
}

// ---------------------------------------------------------------------------
// K5: scan pass 2 — combine chunk carries
// ---------------------------------------------------------------------------
__global__ __launch_bounds__(256) void k5_carry(
    const float* __restrict__ apb, const float* __restrict__ heb,
    float* __restrict__ cin) {
  int t = blockIdx.x * 256 + threadIdx.x;
  if (t >= Bn * Kn * Din) return;
  int bk = t / Din, d = t % Din;
  float c = 0.f;
  for (int ch = 0; ch < NCH; ++ch) {
    size_t o = ((size_t)bk * NCH + ch) * Din + d;
    cin[o] = c;
    c = fmaf(apb[o], c, heb[o]);
  }
}

// ---------------------------------------------------------------------------
// K6: scan pass 3 — recurrence with carry-in, atomic merge into yacc
// ---------------------------------------------------------------------------
__global__ __launch_bounds__(192) void k6_scan2(
    const float* __restrict__ ut, const float* __restrict__ dblp,
    const float* __restrict__ wdtg, const float* __restrict__ bdtg,
    const float* __restrict__ alog, const float* __restrict__ dsg,
    const float* __restrict__ cin, float* __restrict__ yacc) {
  const int bid = blockIdx.x;
  const int ch = bid & (NCH - 1);
  const int bk = bid / NCH;
  const int b = bk >> 2, k = bk & 3;
  const int d = threadIdx.x;

  float wdt[6];
#pragma unroll
  for (int r = 0; r < 6; ++r) wdt[r] = wdtg[(k * Din + d) * 6 + r];
  const float bdt = bdtg[k * Din + d];
  const float Av = -expf(alog[k * Din + d]);
  const float Dv = dsg[k * Din + d];

  const float* utb = &ut[(size_t)b * Ln * Din];
  const float* dbb = &dblp[(size_t)b * Ln * 32 + k * 8];
  float* yb = &yacc[(size_t)b * Ln * Din];

  float h = cin[((size_t)bk * NCH + ch) * Din + d];
  for (int i = 0; i < CLEN; ++i) {
    int l = ch * CLEN + i;
    int p = scan_pixel(k, l);
    const float* dl = &dbb[(size_t)p * 32];
    float4 q0 = *reinterpret_cast<const float4*>(dl);
    float4 q1 = *reinterpret_cast<const float4*>(dl + 4);
    float xdt = bdt;
    xdt = fmaf(q0.x, wdt[0], xdt); xdt = fmaf(q0.y, wdt[1], xdt);
    xdt = fmaf(q0.z, wdt[2], xdt); xdt = fmaf(q0.w, wdt[3], xdt);
    xdt = fmaf(q1.x, wdt[4], xdt); xdt = fmaf(q1.y, wdt[5], xdt);
    float dt = softplusf_(xdt);
    float bs = q1.z, cs = q1.w;
    float u = utb[(size_t)p * Din + d];
    float a = expf(dt * Av);
    float bbv = dt * bs * u;
    h = fmaf(a, h, bbv);
    float y = h * cs + Dv * u;
    atomicAdd(&yb[(size_t)p * Din + d], y);
  }
}

// ---------------------------------------------------------------------------
// K7: out_norm LN(192) + out_proj (192->96) + residual -> zt (B,L,96).
// 16 px/block, 256 thr, grid 1024.
// ---------------------------------------------------------------------------
__global__ __launch_bounds__(256) void k7_outproj(
    const float* __restrict__ yacc, const float* __restrict__ gam,
    const float* __restrict__ bet, const float* __restrict__ W,
    const float* __restrict__ x, float* __restrict__ zt) {
  __shared__ float sy[16 * 193];
  const int tid = threadIdx.x;
  const int p0 = blockIdx.x * 16;
  const int b = p0 >> 12, pl0 = p0 & (Ln - 1);

  for (int f = tid; f < 16 * Din; f += 256) {
    int pp = f / Din, d = f % Din;
    sy[pp * 193 + d] = yacc[((size_t)p0 + pp) * Din + d];
  }
  __syncthreads();
  {
    const int pp = tid >> 4, t16 = tid & 15;  // 16 lanes/px, 12 ch each
    float s = 0.f;
    for (int d2 = t16 * 12; d2 < t16 * 12 + 12; ++d2) s += sy[pp * 193 + d2];
    s += __shfl_xor(s, 1, 16); s += __shfl_xor(s, 2, 16);
    s += __shfl_xor(s, 4, 16); s += __shfl_xor(s, 8, 16);
    float m = s * (1.f / 192.f);
    float v = 0.f;
    for (int d2 = t16 * 12; d2 < t16 * 12 + 12; ++d2) {
      float t = sy[pp * 193 + d2] - m; v += t * t;
    }
    v += __shfl_xor(v, 1, 16); v += __shfl_xor(v, 2, 16);
    v += __shfl_xor(v, 4, 16); v += __shfl_xor(v, 8, 16);
    float rs = rsqrtf(v * (1.f / 192.f) + 1e-5f);
    for (int d2 = t16 * 12; d2 < t16 * 12 + 12; ++d2)
      sy[pp * 193 + d2] = (sy[pp * 193 + d2] - m) * rs * gam[d2] + bet[d2];
  }
  __syncthreads();

  // GEMM 16px x 96c, K=192: g=tid&7 -> 2 px, q=tid>>3 (0..31) -> 3 c's
  const int g = tid & 7, q = tid >> 3;
  float acc[2][3];
#pragma unroll
  for (int i = 0; i < 2; ++i)
#pragma unroll
    for (int j = 0; j < 3; ++j) acc[i][j] = 0.f;

  for (int d2 = 0; d2 < Din; ++d2) {
    float yv[2];
#pragma unroll
    for (int i = 0; i < 2; ++i) yv[i] = sy[(2 * g + i) * 193 + d2];
#pragma unroll
    for (int j = 0; j < 3; ++j) {
      float wv = W[(q * 3 + j) * Din + d2];
#pragma unroll
      for (int i = 0; i < 2; ++i) acc[i][j] = fmaf(yv[i], wv, acc[i][j]);
    }
  }
  __syncthreads();
  float* sz = sy;   // reuse as [16][97]
#pragma unroll
  for (int j = 0; j < 3; ++j)
#pragma unroll
    for (int i = 0; i < 2; ++i) sz[(2 * g + i) * 97 + q * 3 + j] = acc[i][j];
  __syncthreads();

  for (int f = tid; f < 16 * 96; f += 256) {
    int pp = f / 96, c = f % 96;
    zt[((size_t)p0 + pp) * 96 + c] =
        sz[pp * 97 + c] + x[((size_t)b * Cn + c) * Ln + pl0 + pp];
  }
}

// ---------------------------------------------------------------------------
// K8: MLP fused, 512 threads, single-phase fc1 (LDS 60.8KB, 2 blocks/CU).
// fc1 tile 4px x 6j; fc2 tile 2px x 3c.
// ---------------------------------------------------------------------------
__global__ __launch_bounds__(512) void k8_mlp(
    const float* __restrict__ zt, const float* __restrict__ g2,
    const float* __restrict__ b2, const float* __restrict__ w1,
    const float* __restrict__ b1f, const float* __restrict__ w2,
    const float* __restrict__ b2f, const float* __restrict__ x,
    float* __restrict__ out) {
  __shared__ float smn[32 * 101];
  __shared__ float sh[32 * 385];
  const int tid = threadIdx.x;
  const int p0 = blockIdx.x * 32;
  const int b = p0 >> 12, pl0 = p0 & (Ln - 1);

  for (int f = tid; f < 32 * 96; f += 512) {
    int pp = f / 96, c = f % 96;
    smn[pp * 101 + c] = zt[((size_t)p0 + pp) * 96 + c];
  }
  __syncthreads();
  {
    const int pp = tid >> 4, t16 = tid & 15;  // 16 lanes/px, 6 ch each
    float s = 0.f;
    for (int c = t16 * 6; c < t16 * 6 + 6; ++c) s += smn[pp * 101 + c];
    s += __shfl_xor(s, 1, 16); s += __shfl_xor(s, 2, 16);
    s += __shfl_xor(s, 4, 16); s += __shfl_xor(s, 8, 16);
    float m = s * (1.f / 96.f);
    float v = 0.f;
    for (int c = t16 * 6; c < t16 * 6 + 6; ++c) {
      float t = smn[pp * 101 + c] - m; v += t * t;
    }
    v += __shfl_xor(v, 1, 16); v += __shfl_xor(v, 2, 16);
    v += __shfl_xor(v, 4, 16); v += __shfl_xor(v, 8, 16);
    float rs = rsqrtf(v * (1.f / 96.f) + 1e-5f);
    for (int c = t16 * 6; c < t16 * 6 + 6; ++c)
      smn[pp * 101 + c] = (smn[pp * 101 + c] - m) * rs * g2[c] + b2[c];
  }
  __syncthreads();

  // fc1: pg=tid&7 -> 4 px, q=tid>>3 (0..63) -> 6 j's of 384
  {
    const int pg = tid & 7, q = tid >> 3;
    float acc[4][6];
#pragma unroll
    for (int i = 0; i < 4; ++i)
#pragma unroll
      for (int j = 0; j < 6; ++j) acc[i][j] = 0.f;
    for (int c = 0; c < 96; ++c) {
      float mv[4];
#pragma unroll
      for (int i = 0; i < 4; ++i) mv[i] = smn[(4 * pg + i) * 101 + c];
#pragma unroll
      for (int j = 0; j < 6; ++j) {
        float wv = w1[(size_t)(q * 6 + j) * 96 + c];
#pragma unroll
        for (int i = 0; i < 4; ++i) acc[i][j] = fmaf(mv[i], wv, acc[i][j]);
      }
    }
#pragma unroll
    for (int j = 0; j < 6; ++j) {
      int jj = q * 6 + j;
      float bj = b1f[jj];
#pragma unroll
      for (int i = 0; i < 4; ++i)
        sh[(4 * pg + i) * 385 + jj] = geluf_(acc[i][j] + bj);
    }
  }
  __syncthreads();

  // fc2: g=tid&15 -> 2 px, q=tid>>4 (0..31) -> 3 c's
  {
    const int g = tid & 15, q = tid >> 4;
    float a2[2][3];
#pragma unroll
    for (int i = 0; i < 2; ++i)
#pragma unroll
      for (int cc = 0; cc < 3; ++cc) a2[i][cc] = 0.f;
    for (int kl = 0; kl < 384; ++kl) {
      float hv[2];
#pragma unroll
      for (int i = 0; i < 2; ++i) hv[i] = sh[(2 * g + i) * 385 + kl];
#pragma unroll
      for (int cc = 0; cc < 3; ++cc) {
        float wv = w2[(size_t)(q * 3 + cc) * 384 + kl];
#pragma unroll
        for (int i = 0; i < 2; ++i) a2[i][cc] = fmaf(hv[i], wv, a2[i][cc]);
      }
    }
    // smn free (fc1 readers finished before sh barrier); stage MLP out
#pragma unroll
    for (int cc = 0; cc < 3; ++cc)
#pragma unroll
      for (int i = 0; i < 2; ++i)
        smn[(2 * g + i) * 101 + q * 3 + cc] = a2[i][cc] + b2f[q * 3 + cc];
  }
  __syncthreads();

  for (int f = tid; f < 32 * 96; f += 512) {
    int c = f >> 5, pp = f & 31;
    size_t xi = ((size_t)b * Cn + c) * Ln + pl0 + pp;
    out[xi] = x[xi] + zt[((size_t)p0 + pp) * 96 + c] + smn[pp * 101 + c];
  }
}

}  // namespace

extern "C" void kernel_launch(void* const* d_in, const int* in_sizes, int n_in,
                              void* d_out, int out_size, void* d_ws,
                              size_t ws_size, hipStream_t stream) {
  const float* x        = (const float*)d_in[0];
  const float* norm1_g  = (const float*)d_in[1];
  const float* norm1_b  = (const float*)d_in[2];
  const float* in_proj  = (const float*)d_in[3];
  const float* conv_w   = (const float*)d_in[4];
  const float* x_proj   = (const float*)d_in[5];
  const float* dt_w     = (const float*)d_in[6];
  const float* dt_b     = (const float*)d_in[7];
  const float* A_logs   = (const float*)d_in[8];
  const float* Ds       = (const float*)d_in[9];
  const float* onorm_g  = (const float*)d_in[10];
  const float* onorm_b  = (const float*)d_in[11];
  const float* out_proj = (const float*)d_in[12];
  const float* norm2_g  = (const float*)d_in[13];
  const float* norm2_b  = (const float*)d_in[14];
  const float* fc1_w    = (const float*)d_in[15];
  const float* fc1_b    = (const float*)d_in[16];
  const float* fc2_w    = (const float*)d_in[17];
  const float* fc2_b    = (const float*)d_in[18];
  float* out = (float*)d_out;

  float* ws = (float*)d_ws;
  size_t o = 0;
  float* ucp  = ws + o; o += (size_t)Bn * Din * Ln;
  float* ut   = ws + o; o += (size_t)Bn * Ln * Din;
  float* dblp = ws + o; o += (size_t)Bn * Ln * 32;
  float* apb  = ws + o; o += (size_t)Bn * Kn * NCH * Din;
  float* heb  = ws + o; o += (size_t)Bn * Kn * NCH * Din;
  float* cin  = ws + o; o += (size_t)Bn * Kn * NCH * Din;
  float* yacc = ws + o; o += (size_t)Bn * Ln * Din;
  float* zt   = ws + o; o += (size_t)Bn * Ln * Cn;

  hipMemsetAsync(yacc, 0, (size_t)Bn * Ln * Din * sizeof(float), stream);

  k1_ln_inproj<<<1024, 256, 0, stream>>>(x, norm1_g, norm1_b, in_proj, ucp);
  k2_conv_proj<<<Bn * Hn, 512, 0, stream>>>(ucp, conv_w, x_proj, ut, dblp);
  k4_scan1<<<Bn * Kn * NCH, 192, 0, stream>>>(ut, dblp, dt_w, dt_b, A_logs,
                                              apb, heb);
  k5_carry<<<12, 256, 0, stream>>>(apb, heb, cin);
  k6_scan2<<<Bn * Kn * NCH, 192, 0, stream>>>(ut, dblp, dt_w, dt_b, A_logs, Ds,
                                              cin, yacc);
  k7_outproj<<<1024, 256, 0, stream>>>(yacc, onorm_g, onorm_b, out_proj, x, zt);
  k8_mlp<<<512, 512, 0, stream>>>(zt, norm2_g, norm2_b, fc1_w, fc1_b, fc2_w,
                                  fc2_b, x, out);
}

// Round 5
// 221.216 us; speedup vs baseline: 1.5559x; 1.5559x over previous
//
#include <hip/hip_runtime.h>
#include <math.h>

namespace {

constexpr int Bn = 4, Cn = 96, Hn = 64, Wn = 64, Ln = 4096, Din = 192;
constexpr int Kn = 4, Rn = 6, Dmlp = 384;
constexpr int NCH = 128, CLEN = 32;   // 128 chunks * 32 = L

__device__ __forceinline__ float softplusf_(float x) {
  return fmaxf(x, 0.f) + __logf(1.f + __expf(-fabsf(x)));
}
__device__ __forceinline__ float siluf_(float x) {
  return x / (1.f + __expf(-x));
}
__device__ __forceinline__ float geluf_(float x) {
  return 0.5f * x * (1.f + erff(x * 0.7071067811865476f));
}

// ---------------------------------------------------------------------------
// K1: LayerNorm(96) + in_proj (96->192). 32 px/block, 256 thr, grid 512.
// ---------------------------------------------------------------------------
__global__ __launch_bounds__(256) void k1_ln_inproj(
    const float* __restrict__ x, const float* __restrict__ gam,
    const float* __restrict__ bet, const float* __restrict__ W,
    float* __restrict__ ucp) {
  __shared__ float sx[32 * 97];
  const int tid = threadIdx.x;
  const int p0 = blockIdx.x * 32;
  const int b = p0 >> 12, pl0 = p0 & (Ln - 1);

  for (int f = tid; f < 32 * 96; f += 256) {
    int c = f >> 5, pp = f & 31;
    sx[pp * 97 + c] = x[((size_t)b * Cn + c) * Ln + pl0 + pp];
  }
  __syncthreads();
  {
    const int pp = tid >> 3, t8 = tid & 7;   // 8 lanes/pixel, 12 ch each
    float s = 0.f;
    for (int c = t8 * 12; c < t8 * 12 + 12; ++c) s += sx[pp * 97 + c];
    s += __shfl_xor(s, 1, 8); s += __shfl_xor(s, 2, 8); s += __shfl_xor(s, 4, 8);
    float m = s * (1.f / 96.f);
    float v = 0.f;
    for (int c = t8 * 12; c < t8 * 12 + 12; ++c) {
      float t = sx[pp * 97 + c] - m; v += t * t;
    }
    v += __shfl_xor(v, 1, 8); v += __shfl_xor(v, 2, 8); v += __shfl_xor(v, 4, 8);
    float rs = rsqrtf(v * (1.f / 96.f) + 1e-5f);
    for (int c = t8 * 12; c < t8 * 12 + 12; ++c)
      sx[pp * 97 + c] = (sx[pp * 97 + c] - m) * rs * gam[c] + bet[c];
  }
  __syncthreads();

  // GEMM 32px x 192j: pg=tid&7 -> 4 px, q=tid>>3 (0..31) -> 6 j's
  const int pg = tid & 7, q = tid >> 3;
  float acc[4][6];
#pragma unroll
  for (int i = 0; i < 4; ++i)
#pragma unroll
    for (int j = 0; j < 6; ++j) acc[i][j] = 0.f;

  for (int c = 0; c < 96; ++c) {
    float xv[4];
#pragma unroll
    for (int i = 0; i < 4; ++i) xv[i] = sx[(4 * pg + i) * 97 + c];
#pragma unroll
    for (int j = 0; j < 6; ++j) {
      float wv = W[(q * 6 + j) * 96 + c];
#pragma unroll
      for (int i = 0; i < 4; ++i) acc[i][j] = fmaf(xv[i], wv, acc[i][j]);
    }
  }
#pragma unroll
  for (int j = 0; j < 6; ++j) {
    int jj = q * 6 + j;
    float4 v = make_float4(acc[0][j], acc[1][j], acc[2][j], acc[3][j]);
    *reinterpret_cast<float4*>(
        &ucp[((size_t)b * Din + jj) * Ln + pl0 + 4 * pg]) = v;
  }
}

// ---------------------------------------------------------------------------
// K2a: depthwise 3x3 conv + SiLU -> ut (pixel-major). Channel-split:
// grid = B*H*2 (512 blocks), 512 threads, 12 ch/thread. 16 waves/CU.
// ---------------------------------------------------------------------------
__global__ __launch_bounds__(512) void k2a_conv(
    const float* __restrict__ ucp, const float* __restrict__ cw,
    float* __restrict__ ut) {
  __shared__ float su[64 * 97];
  const int tid = threadIdx.x;
  const int bid = blockIdx.x;
  const int half = bid & 1, bh = bid >> 1;
  const int b = bh >> 6, h = bh & 63;
  const int w = tid & 63, wg = tid >> 6;   // 8 groups x 12 ch
  const int d0 = half * 96;

  for (int dd = 0; dd < 12; ++dd) {
    int dl = wg * 12 + dd;
    int d = d0 + dl;
    const float* base = &ucp[((size_t)b * Din + d) * Ln];
    float r0 = (h > 0) ? base[(h - 1) * 64 + w] : 0.f;
    float r1 = base[h * 64 + w];
    float r2 = (h < 63) ? base[(h + 1) * 64 + w] : 0.f;
    const float* wt = &cw[d * 9];
    float rl, rr, acc;
    rl = __shfl(r0, (w + 63) & 63); if (w == 0) rl = 0.f;
    rr = __shfl(r0, (w + 1) & 63);  if (w == 63) rr = 0.f;
    acc = rl * wt[0] + r0 * wt[1] + rr * wt[2];
    rl = __shfl(r1, (w + 63) & 63); if (w == 0) rl = 0.f;
    rr = __shfl(r1, (w + 1) & 63);  if (w == 63) rr = 0.f;
    acc += rl * wt[3] + r1 * wt[4] + rr * wt[5];
    rl = __shfl(r2, (w + 63) & 63); if (w == 0) rl = 0.f;
    rr = __shfl(r2, (w + 1) & 63);  if (w == 63) rr = 0.f;
    acc += rl * wt[6] + r2 * wt[7] + rr * wt[8];
    su[w * 97 + dl] = siluf_(acc);
  }
  __syncthreads();

  for (int f = tid; f < 64 * 96; f += 512) {
    int pp = f / 96, dl = f % 96;
    ut[((size_t)b * Ln + h * 64 + pp) * Din + d0 + dl] = su[pp * 97 + dl];
  }
}

// ---------------------------------------------------------------------------
// K2b: x_proj GEMM: dblp[p, q] = sum_d ut[p,d] * xw[q,d], q = k*8+j (32 outs).
// 32 px/block (grid 512), 256 thr; ut tile + xw staged in padded LDS.
// ---------------------------------------------------------------------------
__global__ __launch_bounds__(256) void k2b_xproj(
    const float* __restrict__ ut, const float* __restrict__ xw,
    float* __restrict__ dblp) {
  __shared__ float su[32 * 193];
  __shared__ float sw[32 * 193];
  const int tid = threadIdx.x;
  const int p0 = blockIdx.x * 32;   // global pixel index over B*L

  for (int f = tid; f < 32 * 192; f += 256) {
    int pp = f / 192, d = f % 192;
    su[pp * 193 + d] = ut[(size_t)(p0 + pp) * 192 + d];
    sw[pp * 193 + d] = xw[f];       // xw is (32, 192) flat
  }
  __syncthreads();

  const int q = tid & 31, pg = tid >> 5;  // 8 groups x 4 px, 1 out each
  float a4[4] = {0.f, 0.f, 0.f, 0.f};
  for (int d = 0; d < 192; ++d) {
    float wv = sw[q * 193 + d];     // bank (q+d)%32: conflict-free
#pragma unroll
    for (int i = 0; i < 4; ++i)
      a4[i] = fmaf(su[(4 * pg + i) * 193 + d], wv, a4[i]);
  }
#pragma unroll
  for (int i = 0; i < 4; ++i)
    dblp[(size_t)(p0 + 4 * pg + i) * 32 + q] = a4[i];
}

__device__ __forceinline__ int scan_pixel(int k, int l) {
  if (k == 0) return l;
  if (k == 1) return ((l & 63) << 6) | (l >> 6);
  if (k == 2) return Ln - 1 - l;
  int m2 = Ln - 1 - l;
  return ((m2 & 63) << 6) | (m2 >> 6);
}

// ---------------------------------------------------------------------------
// K4: scan pass 1
// ---------------------------------------------------------------------------
__global__ __launch_bounds__(192) void k4_scan1(
    const float* __restrict__ ut, const float* __restrict__ dblp,
    const float* __restrict__ wdtg, const float* __restrict__ bdtg,
    const float* __restrict__ alog, float* __restrict__ apb,
    float* __restrict__ heb) {
  const int bid = blockIdx.x;
  const int ch = bid & (NCH - 1);
  const int bk = bid / NCH;
  const int b = bk >> 2, k = bk & 3;
  const int d = threadIdx.x;

  float wdt[6];
#pragma unroll
  for (int r = 0; r < 6; ++r) wdt[r] = wdtg[(k * Din + d) * 6 + r];
  const float bdt = bdtg[k * Din + d];
  const float Av = -__expf(alog[k * Din + d]);

  const float* utb = &ut[(size_t)b * Ln * Din];
  const float* dbb = &dblp[(size_t)b * Ln * 32 + k * 8];

  float h = 0.f, ap = 1.f;
  for (int i = 0; i < CLEN; ++i) {
    int l = ch * CLEN + i;
    int p = scan_pixel(k, l);
    const float* dl = &dbb[(size_t)p * 32];
    float4 q0 = *reinterpret_cast<const float4*>(dl);
    float4 q1 = *reinterpret_cast<const float4*>(dl + 4);
    float xdt = bdt;
    xdt = fmaf(q0.x, wdt[0], xdt); xdt = fmaf(q0.y, wdt[1], xdt);
    xdt = fmaf(q0.z, wdt[2], xdt); xdt = fmaf(q0.w, wdt[3], xdt);
    xdt = fmaf(q1.x, wdt[4], xdt); xdt = fmaf(q1.y, wdt[5], xdt);
    float dt = softplusf_(xdt);
    float bs = q1.z;
    float u = utb[(size_t)p * Din + d];
    float a = __expf(dt * Av);
    float bbv = dt * bs * u;
    h = fmaf(a, h, bbv);
    ap *= a;
  }
  size_t o = ((size_t)bk * NCH + ch) * Din + d;
  apb[o] = ap;
  heb[o] = h;
}

// ---------------------------------------------------------------------------
// K5: scan pass 2 — combine chunk carries
// ---------------------------------------------------------------------------
__global__ __launch_bounds__(256) void k5_carry(
    const float* __restrict__ apb, const float* __restrict__ heb,
    float* __restrict__ cin) {
  int t = blockIdx.x * 256 + threadIdx.x;
  if (t >= Bn * Kn * Din) return;
  int bk = t / Din, d = t % Din;
  float c = 0.f;
  for (int ch = 0; ch < NCH; ++ch) {
    size_t o = ((size_t)bk * NCH + ch) * Din + d;
    cin[o] = c;
    c = fmaf(apb[o], c, heb[o]);
  }
}

// ---------------------------------------------------------------------------
// K6: scan pass 3 — recurrence with carry-in, atomic merge into yacc
// ---------------------------------------------------------------------------
__global__ __launch_bounds__(192) void k6_scan2(
    const float* __restrict__ ut, const float* __restrict__ dblp,
    const float* __restrict__ wdtg, const float* __restrict__ bdtg,
    const float* __restrict__ alog, const float* __restrict__ dsg,
    const float* __restrict__ cin, float* __restrict__ yacc) {
  const int bid = blockIdx.x;
  const int ch = bid & (NCH - 1);
  const int bk = bid / NCH;
  const int b = bk >> 2, k = bk & 3;
  const int d = threadIdx.x;

  float wdt[6];
#pragma unroll
  for (int r = 0; r < 6; ++r) wdt[r] = wdtg[(k * Din + d) * 6 + r];
  const float bdt = bdtg[k * Din + d];
  const float Av = -__expf(alog[k * Din + d]);
  const float Dv = dsg[k * Din + d];

  const float* utb = &ut[(size_t)b * Ln * Din];
  const float* dbb = &dblp[(size_t)b * Ln * 32 + k * 8];
  float* yb = &yacc[(size_t)b * Ln * Din];

  float h = cin[((size_t)bk * NCH + ch) * Din + d];
  for (int i = 0; i < CLEN; ++i) {
    int l = ch * CLEN + i;
    int p = scan_pixel(k, l);
    const float* dl = &dbb[(size_t)p * 32];
    float4 q0 = *reinterpret_cast<const float4*>(dl);
    float4 q1 = *reinterpret_cast<const float4*>(dl + 4);
    float xdt = bdt;
    xdt = fmaf(q0.x, wdt[0], xdt); xdt = fmaf(q0.y, wdt[1], xdt);
    xdt = fmaf(q0.z, wdt[2], xdt); xdt = fmaf(q0.w, wdt[3], xdt);
    xdt = fmaf(q1.x, wdt[4], xdt); xdt = fmaf(q1.y, wdt[5], xdt);
    float dt = softplusf_(xdt);
    float bs = q1.z, cs = q1.w;
    float u = utb[(size_t)p * Din + d];
    float a = __expf(dt * Av);
    float bbv = dt * bs * u;
    h = fmaf(a, h, bbv);
    float y = h * cs + Dv * u;
    atomicAdd(&yb[(size_t)p * Din + d], y);
  }
}

// ---------------------------------------------------------------------------
// K7: out_norm LN(192) + out_proj (192->96) + residual -> zt (B,L,96).
// 32 px/block, 256 thr, grid 512. Tile 4px x 3c.
// ---------------------------------------------------------------------------
__global__ __launch_bounds__(256) void k7_outproj(
    const float* __restrict__ yacc, const float* __restrict__ gam,
    const float* __restrict__ bet, const float* __restrict__ W,
    const float* __restrict__ x, float* __restrict__ zt) {
  __shared__ float sy[32 * 193];
  const int tid = threadIdx.x;
  const int p0 = blockIdx.x * 32;
  const int b = p0 >> 12, pl0 = p0 & (Ln - 1);

  for (int f = tid; f < 32 * 192; f += 256) {
    int pp = f / 192, d = f % 192;
    sy[pp * 193 + d] = yacc[((size_t)p0 + pp) * 192 + d];
  }
  __syncthreads();
  {
    const int pp = tid >> 3, t8 = tid & 7;   // 8 lanes/px, 24 ch each
    float s = 0.f;
    for (int d2 = t8 * 24; d2 < t8 * 24 + 24; ++d2) s += sy[pp * 193 + d2];
    s += __shfl_xor(s, 1, 8); s += __shfl_xor(s, 2, 8); s += __shfl_xor(s, 4, 8);
    float m = s * (1.f / 192.f);
    float v = 0.f;
    for (int d2 = t8 * 24; d2 < t8 * 24 + 24; ++d2) {
      float t = sy[pp * 193 + d2] - m; v += t * t;
    }
    v += __shfl_xor(v, 1, 8); v += __shfl_xor(v, 2, 8); v += __shfl_xor(v, 4, 8);
    float rs = rsqrtf(v * (1.f / 192.f) + 1e-5f);
    for (int d2 = t8 * 24; d2 < t8 * 24 + 24; ++d2)
      sy[pp * 193 + d2] = (sy[pp * 193 + d2] - m) * rs * gam[d2] + bet[d2];
  }
  __syncthreads();

  // GEMM 32px x 96c, K=192: pg=tid&7 -> 4 px, q=tid>>3 (0..31) -> 3 c's
  const int pg = tid & 7, q = tid >> 3;
  float acc[4][3];
#pragma unroll
  for (int i = 0; i < 4; ++i)
#pragma unroll
    for (int j = 0; j < 3; ++j) acc[i][j] = 0.f;

  for (int d2 = 0; d2 < Din; ++d2) {
    float yv[4];
#pragma unroll
    for (int i = 0; i < 4; ++i) yv[i] = sy[(4 * pg + i) * 193 + d2];
#pragma unroll
    for (int j = 0; j < 3; ++j) {
      float wv = W[(q * 3 + j) * Din + d2];
#pragma unroll
      for (int i = 0; i < 4; ++i) acc[i][j] = fmaf(yv[i], wv, acc[i][j]);
    }
  }
  __syncthreads();
  float* sz = sy;   // reuse as [32][97]
#pragma unroll
  for (int j = 0; j < 3; ++j)
#pragma unroll
    for (int i = 0; i < 4; ++i) sz[(4 * pg + i) * 97 + q * 3 + j] = acc[i][j];
  __syncthreads();

  for (int f = tid; f < 32 * 96; f += 256) {
    int pp = f / 96, c = f % 96;
    zt[((size_t)p0 + pp) * 96 + c] =
        sz[pp * 97 + c] + x[((size_t)b * Cn + c) * Ln + pl0 + pp];
  }
}

// ---------------------------------------------------------------------------
// K8: MLP fused, 512 threads, single-phase fc1 (LDS 60.8KB, 2 blocks/CU).
// ---------------------------------------------------------------------------
__global__ __launch_bounds__(512) void k8_mlp(
    const float* __restrict__ zt, const float* __restrict__ g2,
    const float* __restrict__ b2, const float* __restrict__ w1,
    const float* __restrict__ b1f, const float* __restrict__ w2,
    const float* __restrict__ b2f, const float* __restrict__ x,
    float* __restrict__ out) {
  __shared__ float smn[32 * 101];
  __shared__ float sh[32 * 385];
  const int tid = threadIdx.x;
  const int p0 = blockIdx.x * 32;
  const int b = p0 >> 12, pl0 = p0 & (Ln - 1);

  for (int f = tid; f < 32 * 96; f += 512) {
    int pp = f / 96, c = f % 96;
    smn[pp * 101 + c] = zt[((size_t)p0 + pp) * 96 + c];
  }
  __syncthreads();
  {
    const int pp = tid >> 4, t16 = tid & 15;  // 16 lanes/px, 6 ch each
    float s = 0.f;
    for (int c = t16 * 6; c < t16 * 6 + 6; ++c) s += smn[pp * 101 + c];
    s += __shfl_xor(s, 1, 16); s += __shfl_xor(s, 2, 16);
    s += __shfl_xor(s, 4, 16); s += __shfl_xor(s, 8, 16);
    float m = s * (1.f / 96.f);
    float v = 0.f;
    for (int c = t16 * 6; c < t16 * 6 + 6; ++c) {
      float t = smn[pp * 101 + c] - m; v += t * t;
    }
    v += __shfl_xor(v, 1, 16); v += __shfl_xor(v, 2, 16);
    v += __shfl_xor(v, 4, 16); v += __shfl_xor(v, 8, 16);
    float rs = rsqrtf(v * (1.f / 96.f) + 1e-5f);
    for (int c = t16 * 6; c < t16 * 6 + 6; ++c)
      smn[pp * 101 + c] = (smn[pp * 101 + c] - m) * rs * g2[c] + b2[c];
  }
  __syncthreads();

  // fc1: pg=tid&7 -> 4 px, q=tid>>3 (0..63) -> 6 j's of 384
  {
    const int pg = tid & 7, q = tid >> 3;
    float acc[4][6];
#pragma unroll
    for (int i = 0; i < 4; ++i)
#pragma unroll
      for (int j = 0; j < 6; ++j) acc[i][j] = 0.f;
    for (int c = 0; c < 96; ++c) {
      float mv[4];
#pragma unroll
      for (int i = 0; i < 4; ++i) mv[i] = smn[(4 * pg + i) * 101 + c];
#pragma unroll
      for (int j = 0; j < 6; ++j) {
        float wv = w1[(size_t)(q * 6 + j) * 96 + c];
#pragma unroll
        for (int i = 0; i < 4; ++i) acc[i][j] = fmaf(mv[i], wv, acc[i][j]);
      }
    }
#pragma unroll
    for (int j = 0; j < 6; ++j) {
      int jj = q * 6 + j;
      float bj = b1f[jj];
#pragma unroll
      for (int i = 0; i < 4; ++i)
        sh[(4 * pg + i) * 385 + jj] = geluf_(acc[i][j] + bj);
    }
  }
  __syncthreads();

  // fc2: g=tid&15 -> 2 px, q=tid>>4 (0..31) -> 3 c's
  {
    const int g = tid & 15, q = tid >> 4;
    float a2[2][3];
#pragma unroll
    for (int i = 0; i < 2; ++i)
#pragma unroll
      for (int cc = 0; cc < 3; ++cc) a2[i][cc] = 0.f;
    for (int kl = 0; kl < 384; ++kl) {
      float hv[2];
#pragma unroll
      for (int i = 0; i < 2; ++i) hv[i] = sh[(2 * g + i) * 385 + kl];
#pragma unroll
      for (int cc = 0; cc < 3; ++cc) {
        float wv = w2[(size_t)(q * 3 + cc) * 384 + kl];
#pragma unroll
        for (int i = 0; i < 2; ++i) a2[i][cc] = fmaf(hv[i], wv, a2[i][cc]);
      }
    }
#pragma unroll
    for (int cc = 0; cc < 3; ++cc)
#pragma unroll
      for (int i = 0; i < 2; ++i)
        smn[(2 * g + i) * 101 + q * 3 + cc] = a2[i][cc] + b2f[q * 3 + cc];
  }
  __syncthreads();

  for (int f = tid; f < 32 * 96; f += 512) {
    int c = f >> 5, pp = f & 31;
    size_t xi = ((size_t)b * Cn + c) * Ln + pl0 + pp;
    out[xi] = x[xi] + zt[((size_t)p0 + pp) * 96 + c] + smn[pp * 101 + c];
  }
}

}  // namespace

extern "C" void kernel_launch(void* const* d_in, const int* in_sizes, int n_in,
                              void* d_out, int out_size, void* d_ws,
                              size_t ws_size, hipStream_t stream) {
  const float* x        = (const float*)d_in[0];
  const float* norm1_g  = (const float*)d_in[1];
  const float* norm1_b  = (const float*)d_in[2];
  const float* in_proj  = (const float*)d_in[3];
  const float* conv_w   = (const float*)d_in[4];
  const float* x_proj   = (const float*)d_in[5];
  const float* dt_w     = (const float*)d_in[6];
  const float* dt_b     = (const float*)d_in[7];
  const float* A_logs   = (const float*)d_in[8];
  const float* Ds       = (const float*)d_in[9];
  const float* onorm_g  = (const float*)d_in[10];
  const float* onorm_b  = (const float*)d_in[11];
  const float* out_proj = (const float*)d_in[12];
  const float* norm2_g  = (const float*)d_in[13];
  const float* norm2_b  = (const float*)d_in[14];
  const float* fc1_w    = (const float*)d_in[15];
  const float* fc1_b    = (const float*)d_in[16];
  const float* fc2_w    = (const float*)d_in[17];
  const float* fc2_b    = (const float*)d_in[18];
  float* out = (float*)d_out;

  float* ws = (float*)d_ws;
  size_t o = 0;
  float* ucp  = ws + o; o += (size_t)Bn * Din * Ln;
  float* ut   = ws + o; o += (size_t)Bn * Ln * Din;
  float* dblp = ws + o; o += (size_t)Bn * Ln * 32;
  float* apb  = ws + o; o += (size_t)Bn * Kn * NCH * Din;
  float* heb  = ws + o; o += (size_t)Bn * Kn * NCH * Din;
  float* cin  = ws + o; o += (size_t)Bn * Kn * NCH * Din;
  float* yacc = ws + o; o += (size_t)Bn * Ln * Din;
  float* zt   = ws + o; o += (size_t)Bn * Ln * Cn;

  hipMemsetAsync(yacc, 0, (size_t)Bn * Ln * Din * sizeof(float), stream);

  k1_ln_inproj<<<512, 256, 0, stream>>>(x, norm1_g, norm1_b, in_proj, ucp);
  k2a_conv<<<Bn * Hn * 2, 512, 0, stream>>>(ucp, conv_w, ut);
  k2b_xproj<<<512, 256, 0, stream>>>(ut, x_proj, dblp);
  k4_scan1<<<Bn * Kn * NCH, 192, 0, stream>>>(ut, dblp, dt_w, dt_b, A_logs,
                                              apb, heb);
  k5_carry<<<12, 256, 0, stream>>>(apb, heb, cin);
  k6_scan2<<<Bn * Kn * NCH, 192, 0, stream>>>(ut, dblp, dt_w, dt_b, A_logs, Ds,
                                              cin, yacc);
  k7_outproj<<<512, 256, 0, stream>>>(yacc, onorm_g, onorm_b, out_proj, x, zt);
  k8_mlp<<<512, 512, 0, stream>>>(zt, norm2_g, norm2_b, fc1_w, fc1_b, fc2_w,
                                  fc2_b, x, out);
}

// Round 6
// 184.423 us; speedup vs baseline: 1.8663x; 1.1995x over previous
//
#include <hip/hip_runtime.h>
#include <math.h>

namespace {

constexpr int Bn = 4, Cn = 96, Hn = 64, Wn = 64, Ln = 4096, Din = 192;
constexpr int Kn = 4, Rn = 6, Dmlp = 384;
constexpr int NCH = 128, CLEN = 32;   // 128 chunks * 32 = L

typedef short short8 __attribute__((ext_vector_type(8)));
typedef float f32x4 __attribute__((ext_vector_type(4)));

__device__ __forceinline__ float softplusf_(float x) {
  return fmaxf(x, 0.f) + __logf(1.f + __expf(-fabsf(x)));
}
__device__ __forceinline__ float siluf_(float x) {
  return x / (1.f + __expf(-x));
}
__device__ __forceinline__ float geluf_(float x) {
  return 0.5f * x * (1.f + erff(x * 0.7071067811865476f));
}
__device__ __forceinline__ unsigned short f2bf(float f) {
  unsigned u = __float_as_uint(f);
  unsigned r = 0x7fffu + ((u >> 16) & 1u);
  return (unsigned short)((u + r) >> 16);
}

// ---------------------------------------------------------------------------
// KC: convert fc1_w / fc2_w to bf16 (once per launch). 288 blocks x 256.
// ---------------------------------------------------------------------------
__global__ __launch_bounds__(256) void kc_cvt(
    const float* __restrict__ w1, const float* __restrict__ w2,
    unsigned short* __restrict__ w1b, unsigned short* __restrict__ w2b) {
  int t = blockIdx.x * 256 + threadIdx.x;
  if (t < 36864) w1b[t] = f2bf(w1[t]);
  else if (t < 73728) w2b[t - 36864] = f2bf(w2[t - 36864]);
}

// ---------------------------------------------------------------------------
// K1: LayerNorm(96) + in_proj (96->192). 32 px/block, 256 thr, grid 512.
// ---------------------------------------------------------------------------
__global__ __launch_bounds__(256) void k1_ln_inproj(
    const float* __restrict__ x, const float* __restrict__ gam,
    const float* __restrict__ bet, const float* __restrict__ W,
    float* __restrict__ ucp) {
  __shared__ float sx[32 * 97];
  const int tid = threadIdx.x;
  const int p0 = blockIdx.x * 32;
  const int b = p0 >> 12, pl0 = p0 & (Ln - 1);

  for (int f = tid; f < 32 * 96; f += 256) {
    int c = f >> 5, pp = f & 31;
    sx[pp * 97 + c] = x[((size_t)b * Cn + c) * Ln + pl0 + pp];
  }
  __syncthreads();
  {
    const int pp = tid >> 3, t8 = tid & 7;   // 8 lanes/pixel, 12 ch each
    float s = 0.f;
    for (int c = t8 * 12; c < t8 * 12 + 12; ++c) s += sx[pp * 97 + c];
    s += __shfl_xor(s, 1, 8); s += __shfl_xor(s, 2, 8); s += __shfl_xor(s, 4, 8);
    float m = s * (1.f / 96.f);
    float v = 0.f;
    for (int c = t8 * 12; c < t8 * 12 + 12; ++c) {
      float t = sx[pp * 97 + c] - m; v += t * t;
    }
    v += __shfl_xor(v, 1, 8); v += __shfl_xor(v, 2, 8); v += __shfl_xor(v, 4, 8);
    float rs = rsqrtf(v * (1.f / 96.f) + 1e-5f);
    for (int c = t8 * 12; c < t8 * 12 + 12; ++c)
      sx[pp * 97 + c] = (sx[pp * 97 + c] - m) * rs * gam[c] + bet[c];
  }
  __syncthreads();

  const int pg = tid & 7, q = tid >> 3;   // 4 px x 6 j
  float acc[4][6];
#pragma unroll
  for (int i = 0; i < 4; ++i)
#pragma unroll
    for (int j = 0; j < 6; ++j) acc[i][j] = 0.f;

  for (int c = 0; c < 96; ++c) {
    float xv[4];
#pragma unroll
    for (int i = 0; i < 4; ++i) xv[i] = sx[(4 * pg + i) * 97 + c];
#pragma unroll
    for (int j = 0; j < 6; ++j) {
      float wv = W[(q * 6 + j) * 96 + c];
#pragma unroll
      for (int i = 0; i < 4; ++i) acc[i][j] = fmaf(xv[i], wv, acc[i][j]);
    }
  }
#pragma unroll
  for (int j = 0; j < 6; ++j) {
    int jj = q * 6 + j;
    float4 v = make_float4(acc[0][j], acc[1][j], acc[2][j], acc[3][j]);
    *reinterpret_cast<float4*>(
        &ucp[((size_t)b * Din + jj) * Ln + pl0 + 4 * pg]) = v;
  }
}

// ---------------------------------------------------------------------------
// K2a: depthwise 3x3 conv + SiLU -> ut (pixel-major). Channel-split.
// ---------------------------------------------------------------------------
__global__ __launch_bounds__(512) void k2a_conv(
    const float* __restrict__ ucp, const float* __restrict__ cw,
    float* __restrict__ ut) {
  __shared__ float su[64 * 97];
  const int tid = threadIdx.x;
  const int bid = blockIdx.x;
  const int half = bid & 1, bh = bid >> 1;
  const int b = bh >> 6, h = bh & 63;
  const int w = tid & 63, wg = tid >> 6;   // 8 groups x 12 ch
  const int d0 = half * 96;

  for (int dd = 0; dd < 12; ++dd) {
    int dl = wg * 12 + dd;
    int d = d0 + dl;
    const float* base = &ucp[((size_t)b * Din + d) * Ln];
    float r0 = (h > 0) ? base[(h - 1) * 64 + w] : 0.f;
    float r1 = base[h * 64 + w];
    float r2 = (h < 63) ? base[(h + 1) * 64 + w] : 0.f;
    const float* wt = &cw[d * 9];
    float rl, rr, acc;
    rl = __shfl(r0, (w + 63) & 63); if (w == 0) rl = 0.f;
    rr = __shfl(r0, (w + 1) & 63);  if (w == 63) rr = 0.f;
    acc = rl * wt[0] + r0 * wt[1] + rr * wt[2];
    rl = __shfl(r1, (w + 63) & 63); if (w == 0) rl = 0.f;
    rr = __shfl(r1, (w + 1) & 63);  if (w == 63) rr = 0.f;
    acc += rl * wt[3] + r1 * wt[4] + rr * wt[5];
    rl = __shfl(r2, (w + 63) & 63); if (w == 0) rl = 0.f;
    rr = __shfl(r2, (w + 1) & 63);  if (w == 63) rr = 0.f;
    acc += rl * wt[6] + r2 * wt[7] + rr * wt[8];
    su[w * 97 + dl] = siluf_(acc);
  }
  __syncthreads();

  for (int f = tid; f < 64 * 96; f += 512) {
    int pp = f / 96, dl = f % 96;
    ut[((size_t)b * Ln + h * 64 + pp) * Din + d0 + dl] = su[pp * 97 + dl];
  }
}

// ---------------------------------------------------------------------------
// K2b: x_proj GEMM: dblp[p, q] = sum_d ut[p,d] * xw[q,d].
// ---------------------------------------------------------------------------
__global__ __launch_bounds__(256) void k2b_xproj(
    const float* __restrict__ ut, const float* __restrict__ xw,
    float* __restrict__ dblp) {
  __shared__ float su[32 * 193];
  __shared__ float sw[32 * 193];
  const int tid = threadIdx.x;
  const int p0 = blockIdx.x * 32;

  for (int f = tid; f < 32 * 192; f += 256) {
    int pp = f / 192, d = f % 192;
    su[pp * 193 + d] = ut[(size_t)(p0 + pp) * 192 + d];
    sw[pp * 193 + d] = xw[f];
  }
  __syncthreads();

  const int q = tid & 31, pg = tid >> 5;
  float a4[4] = {0.f, 0.f, 0.f, 0.f};
  for (int d = 0; d < 192; ++d) {
    float wv = sw[q * 193 + d];
#pragma unroll
    for (int i = 0; i < 4; ++i)
      a4[i] = fmaf(su[(4 * pg + i) * 193 + d], wv, a4[i]);
  }
#pragma unroll
  for (int i = 0; i < 4; ++i)
    dblp[(size_t)(p0 + 4 * pg + i) * 32 + q] = a4[i];
}

__device__ __forceinline__ int scan_pixel(int k, int l) {
  if (k == 0) return l;
  if (k == 1) return ((l & 63) << 6) | (l >> 6);
  if (k == 2) return Ln - 1 - l;
  int m2 = Ln - 1 - l;
  return ((m2 & 63) << 6) | (m2 >> 6);
}

// ---------------------------------------------------------------------------
// K4: scan pass 1
// ---------------------------------------------------------------------------
__global__ __launch_bounds__(192) void k4_scan1(
    const float* __restrict__ ut, const float* __restrict__ dblp,
    const float* __restrict__ wdtg, const float* __restrict__ bdtg,
    const float* __restrict__ alog, float* __restrict__ apb,
    float* __restrict__ heb) {
  const int bid = blockIdx.x;
  const int ch = bid & (NCH - 1);
  const int bk = bid / NCH;
  const int b = bk >> 2, k = bk & 3;
  const int d = threadIdx.x;

  float wdt[6];
#pragma unroll
  for (int r = 0; r < 6; ++r) wdt[r] = wdtg[(k * Din + d) * 6 + r];
  const float bdt = bdtg[k * Din + d];
  const float Av = -__expf(alog[k * Din + d]);

  const float* utb = &ut[(size_t)b * Ln * Din];
  const float* dbb = &dblp[(size_t)b * Ln * 32 + k * 8];

  float h = 0.f, ap = 1.f;
  for (int i = 0; i < CLEN; ++i) {
    int l = ch * CLEN + i;
    int p = scan_pixel(k, l);
    const float* dl = &dbb[(size_t)p * 32];
    float4 q0 = *reinterpret_cast<const float4*>(dl);
    float4 q1 = *reinterpret_cast<const float4*>(dl + 4);
    float xdt = bdt;
    xdt = fmaf(q0.x, wdt[0], xdt); xdt = fmaf(q0.y, wdt[1], xdt);
    xdt = fmaf(q0.z, wdt[2], xdt); xdt = fmaf(q0.w, wdt[3], xdt);
    xdt = fmaf(q1.x, wdt[4], xdt); xdt = fmaf(q1.y, wdt[5], xdt);
    float dt = softplusf_(xdt);
    float bs = q1.z;
    float u = utb[(size_t)p * Din + d];
    float a = __expf(dt * Av);
    float bbv = dt * bs * u;
    h = fmaf(a, h, bbv);
    ap *= a;
  }
  size_t o = ((size_t)bk * NCH + ch) * Din + d;
  apb[o] = ap;
  heb[o] = h;
}

// ---------------------------------------------------------------------------
// K5: scan pass 2 — combine chunk carries
// ---------------------------------------------------------------------------
__global__ __launch_bounds__(256) void k5_carry(
    const float* __restrict__ apb, const float* __restrict__ heb,
    float* __restrict__ cin) {
  int t = blockIdx.x * 256 + threadIdx.x;
  if (t >= Bn * Kn * Din) return;
  int bk = t / Din, d = t % Din;
  float c = 0.f;
  for (int ch = 0; ch < NCH; ++ch) {
    size_t o = ((size_t)bk * NCH + ch) * Din + d;
    cin[o] = c;
    c = fmaf(apb[o], c, heb[o]);
  }
}

// ---------------------------------------------------------------------------
// K6: scan pass 3 — recurrence with carry-in, atomic merge into yacc
// ---------------------------------------------------------------------------
__global__ __launch_bounds__(192) void k6_scan2(
    const float* __restrict__ ut, const float* __restrict__ dblp,
    const float* __restrict__ wdtg, const float* __restrict__ bdtg,
    const float* __restrict__ alog, const float* __restrict__ dsg,
    const float* __restrict__ cin, float* __restrict__ yacc) {
  const int bid = blockIdx.x;
  const int ch = bid & (NCH - 1);
  const int bk = bid / NCH;
  const int b = bk >> 2, k = bk & 3;
  const int d = threadIdx.x;

  float wdt[6];
#pragma unroll
  for (int r = 0; r < 6; ++r) wdt[r] = wdtg[(k * Din + d) * 6 + r];
  const float bdt = bdtg[k * Din + d];
  const float Av = -__expf(alog[k * Din + d]);
  const float Dv = dsg[k * Din + d];

  const float* utb = &ut[(size_t)b * Ln * Din];
  const float* dbb = &dblp[(size_t)b * Ln * 32 + k * 8];
  float* yb = &yacc[(size_t)b * Ln * Din];

  float h = cin[((size_t)bk * NCH + ch) * Din + d];
  for (int i = 0; i < CLEN; ++i) {
    int l = ch * CLEN + i;
    int p = scan_pixel(k, l);
    const float* dl = &dbb[(size_t)p * 32];
    float4 q0 = *reinterpret_cast<const float4*>(dl);
    float4 q1 = *reinterpret_cast<const float4*>(dl + 4);
    float xdt = bdt;
    xdt = fmaf(q0.x, wdt[0], xdt); xdt = fmaf(q0.y, wdt[1], xdt);
    xdt = fmaf(q0.z, wdt[2], xdt); xdt = fmaf(q0.w, wdt[3], xdt);
    xdt = fmaf(q1.x, wdt[4], xdt); xdt = fmaf(q1.y, wdt[5], xdt);
    float dt = softplusf_(xdt);
    float bs = q1.z, cs = q1.w;
    float u = utb[(size_t)p * Din + d];
    float a = __expf(dt * Av);
    float bbv = dt * bs * u;
    h = fmaf(a, h, bbv);
    float y = h * cs + Dv * u;
    atomicAdd(&yb[(size_t)p * Din + d], y);
  }
}

// ---------------------------------------------------------------------------
// K7: out_norm LN(192) + out_proj (192->96) + residual -> zt (B,L,96).
// ---------------------------------------------------------------------------
__global__ __launch_bounds__(256) void k7_outproj(
    const float* __restrict__ yacc, const float* __restrict__ gam,
    const float* __restrict__ bet, const float* __restrict__ W,
    const float* __restrict__ x, float* __restrict__ zt) {
  __shared__ float sy[32 * 193];
  const int tid = threadIdx.x;
  const int p0 = blockIdx.x * 32;
  const int b = p0 >> 12, pl0 = p0 & (Ln - 1);

  for (int f = tid; f < 32 * 192; f += 256) {
    int pp = f / 192, d = f % 192;
    sy[pp * 193 + d] = yacc[((size_t)p0 + pp) * 192 + d];
  }
  __syncthreads();
  {
    const int pp = tid >> 3, t8 = tid & 7;
    float s = 0.f;
    for (int d2 = t8 * 24; d2 < t8 * 24 + 24; ++d2) s += sy[pp * 193 + d2];
    s += __shfl_xor(s, 1, 8); s += __shfl_xor(s, 2, 8); s += __shfl_xor(s, 4, 8);
    float m = s * (1.f / 192.f);
    float v = 0.f;
    for (int d2 = t8 * 24; d2 < t8 * 24 + 24; ++d2) {
      float t = sy[pp * 193 + d2] - m; v += t * t;
    }
    v += __shfl_xor(v, 1, 8); v += __shfl_xor(v, 2, 8); v += __shfl_xor(v, 4, 8);
    float rs = rsqrtf(v * (1.f / 192.f) + 1e-5f);
    for (int d2 = t8 * 24; d2 < t8 * 24 + 24; ++d2)
      sy[pp * 193 + d2] = (sy[pp * 193 + d2] - m) * rs * gam[d2] + bet[d2];
  }
  __syncthreads();

  const int pg = tid & 7, q = tid >> 3;
  float acc[4][3];
#pragma unroll
  for (int i = 0; i < 4; ++i)
#pragma unroll
    for (int j = 0; j < 3; ++j) acc[i][j] = 0.f;

  for (int d2 = 0; d2 < Din; ++d2) {
    float yv[4];
#pragma unroll
    for (int i = 0; i < 4; ++i) yv[i] = sy[(4 * pg + i) * 193 + d2];
#pragma unroll
    for (int j = 0; j < 3; ++j) {
      float wv = W[(q * 3 + j) * Din + d2];
#pragma unroll
      for (int i = 0; i < 4; ++i) acc[i][j] = fmaf(yv[i], wv, acc[i][j]);
    }
  }
  __syncthreads();
  float* sz = sy;
#pragma unroll
  for (int j = 0; j < 3; ++j)
#pragma unroll
    for (int i = 0; i < 4; ++i) sz[(4 * pg + i) * 97 + q * 3 + j] = acc[i][j];
  __syncthreads();

  for (int f = tid; f < 32 * 96; f += 256) {
    int pp = f / 96, c = f % 96;
    zt[((size_t)p0 + pp) * 96 + c] =
        sz[pp * 97 + c] + x[((size_t)b * Cn + c) * Ln + pl0 + pp];
  }
}

// ---------------------------------------------------------------------------
// K8: MLP via bf16 MFMA. 32 px/block, 256 thr (4 waves), grid 512.
// LN(f32) -> bf16 act -> fc1 (48 16x16 tiles, K=96) -> gelu -> bf16 h ->
// fc2 (12 tiles, K=384) -> f32 + residuals.
// Fragment layout (m89-verified): A/B non-K idx = lane&15, k=(lane>>4)*8+i;
// D: col=lane&15, row=(lane>>4)*4+reg.
// ---------------------------------------------------------------------------
__global__ __launch_bounds__(256) void k8_mfma(
    const float* __restrict__ zt, const float* __restrict__ g2,
    const float* __restrict__ b2, const unsigned short* __restrict__ w1b,
    const float* __restrict__ b1f, const unsigned short* __restrict__ w2b,
    const float* __restrict__ b2f, const float* __restrict__ x,
    float* __restrict__ out) {
  __shared__ __align__(16) float szt[32 * 101];            // LN buf, reused for out
  __shared__ __align__(16) unsigned short sm[32 * 104];    // bf16 activations
  __shared__ __align__(16) unsigned short sh[32 * 392];    // bf16 hidden
  const int tid = threadIdx.x;
  const int p0 = blockIdx.x * 32;
  const int b = p0 >> 12, pl0 = p0 & (Ln - 1);

  for (int f = tid; f < 32 * 96; f += 256) {
    int pp = f / 96, c = f % 96;
    szt[pp * 101 + c] = zt[((size_t)p0 + pp) * 96 + c];
  }
  __syncthreads();
  {
    const int pp = tid >> 3, t8 = tid & 7;   // 8 lanes/px, 12 ch each
    float s = 0.f;
    for (int c = t8 * 12; c < t8 * 12 + 12; ++c) s += szt[pp * 101 + c];
    s += __shfl_xor(s, 1, 8); s += __shfl_xor(s, 2, 8); s += __shfl_xor(s, 4, 8);
    float m = s * (1.f / 96.f);
    float v = 0.f;
    for (int c = t8 * 12; c < t8 * 12 + 12; ++c) {
      float t = szt[pp * 101 + c] - m; v += t * t;
    }
    v += __shfl_xor(v, 1, 8); v += __shfl_xor(v, 2, 8); v += __shfl_xor(v, 4, 8);
    float rs = rsqrtf(v * (1.f / 96.f) + 1e-5f);
    for (int c = t8 * 12; c < t8 * 12 + 12; ++c)
      szt[pp * 101 + c] = (szt[pp * 101 + c] - m) * rs * g2[c] + b2[c];
  }
  __syncthreads();
  for (int f = tid; f < 32 * 96; f += 256) {
    int pp = f / 96, c = f % 96;
    sm[pp * 104 + c] = f2bf(szt[pp * 101 + c]);
  }
  __syncthreads();

  const int wv = tid >> 6;           // wave 0..3
  const int lane = tid & 63;
  const int l15 = lane & 15, lhi = lane >> 4;   // lhi 0..3

  // ---- fc1: D[px][j] = act @ w1^T. 2 m-tiles x 24 n-tiles, K=96 ----
  {
    const int mt = wv & 1;
    const int ngrp = (wv >> 1) * 12;
    for (int t = 0; t < 12; ++t) {
      const int n0 = (ngrp + t) * 16;
      f32x4 acc = {0.f, 0.f, 0.f, 0.f};
#pragma unroll
      for (int kk = 0; kk < 3; ++kk) {
        short8 av = *reinterpret_cast<const short8*>(
            &sm[(16 * mt + l15) * 104 + kk * 32 + lhi * 8]);
        short8 bv = *reinterpret_cast<const short8*>(
            &w1b[(size_t)(n0 + l15) * 96 + kk * 32 + lhi * 8]);
        acc = __builtin_amdgcn_mfma_f32_16x16x32_bf16(av, bv, acc, 0, 0, 0);
      }
      const int j = n0 + l15;
      const float bj = b1f[j];
#pragma unroll
      for (int r = 0; r < 4; ++r) {
        int px = 16 * mt + lhi * 4 + r;
        sh[px * 392 + j] = f2bf(geluf_(acc[r] + bj));
      }
    }
  }
  __syncthreads();

  // ---- fc2: D[px][c] = h @ w2^T. 12 tiles (2m x 6n), K=384 ----
  {
    for (int tt = wv; tt < 12; tt += 4) {
      const int mt = tt & 1, nt = tt >> 1;
      const int c0 = nt * 16;
      f32x4 acc = {0.f, 0.f, 0.f, 0.f};
#pragma unroll
      for (int kk = 0; kk < 12; ++kk) {
        short8 av = *reinterpret_cast<const short8*>(
            &sh[(16 * mt + l15) * 392 + kk * 32 + lhi * 8]);
        short8 bv = *reinterpret_cast<const short8*>(
            &w2b[(size_t)(c0 + l15) * 384 + kk * 32 + lhi * 8]);
        acc = __builtin_amdgcn_mfma_f32_16x16x32_bf16(av, bv, acc, 0, 0, 0);
      }
      const int c = c0 + l15;
      const float bc = b2f[c];
#pragma unroll
      for (int r = 0; r < 4; ++r) {
        int px = 16 * mt + lhi * 4 + r;
        szt[px * 101 + c] = acc[r] + bc;
      }
    }
  }
  __syncthreads();

  // out[b,c,p] = x + zt + mlp
  for (int f = tid; f < 32 * 96; f += 256) {
    int c = f >> 5, pp = f & 31;
    size_t xi = ((size_t)b * Cn + c) * Ln + pl0 + pp;
    out[xi] = x[xi] + zt[((size_t)p0 + pp) * 96 + c] + szt[pp * 101 + c];
  }
}

}  // namespace

extern "C" void kernel_launch(void* const* d_in, const int* in_sizes, int n_in,
                              void* d_out, int out_size, void* d_ws,
                              size_t ws_size, hipStream_t stream) {
  const float* x        = (const float*)d_in[0];
  const float* norm1_g  = (const float*)d_in[1];
  const float* norm1_b  = (const float*)d_in[2];
  const float* in_proj  = (const float*)d_in[3];
  const float* conv_w   = (const float*)d_in[4];
  const float* x_proj   = (const float*)d_in[5];
  const float* dt_w     = (const float*)d_in[6];
  const float* dt_b     = (const float*)d_in[7];
  const float* A_logs   = (const float*)d_in[8];
  const float* Ds       = (const float*)d_in[9];
  const float* onorm_g  = (const float*)d_in[10];
  const float* onorm_b  = (const float*)d_in[11];
  const float* out_proj = (const float*)d_in[12];
  const float* norm2_g  = (const float*)d_in[13];
  const float* norm2_b  = (const float*)d_in[14];
  const float* fc1_w    = (const float*)d_in[15];
  const float* fc1_b    = (const float*)d_in[16];
  const float* fc2_w    = (const float*)d_in[17];
  const float* fc2_b    = (const float*)d_in[18];
  float* out = (float*)d_out;

  float* ws = (float*)d_ws;
  size_t o = 0;
  float* ucp  = ws + o; o += (size_t)Bn * Din * Ln;
  float* ut   = ws + o; o += (size_t)Bn * Ln * Din;
  float* dblp = ws + o; o += (size_t)Bn * Ln * 32;
  float* apb  = ws + o; o += (size_t)Bn * Kn * NCH * Din;
  float* heb  = ws + o; o += (size_t)Bn * Kn * NCH * Din;
  float* cin  = ws + o; o += (size_t)Bn * Kn * NCH * Din;
  float* yacc = ws + o; o += (size_t)Bn * Ln * Din;
  float* zt   = ws + o; o += (size_t)Bn * Ln * Cn;
  unsigned short* w1b = (unsigned short*)(ws + o); o += 36864 / 2;
  unsigned short* w2b = (unsigned short*)(ws + o); o += 36864 / 2;

  hipMemsetAsync(yacc, 0, (size_t)Bn * Ln * Din * sizeof(float), stream);

  kc_cvt<<<288, 256, 0, stream>>>(fc1_w, fc2_w, w1b, w2b);
  k1_ln_inproj<<<512, 256, 0, stream>>>(x, norm1_g, norm1_b, in_proj, ucp);
  k2a_conv<<<Bn * Hn * 2, 512, 0, stream>>>(ucp, conv_w, ut);
  k2b_xproj<<<512, 256, 0, stream>>>(ut, x_proj, dblp);
  k4_scan1<<<Bn * Kn * NCH, 192, 0, stream>>>(ut, dblp, dt_w, dt_b, A_logs,
                                              apb, heb);
  k5_carry<<<12, 256, 0, stream>>>(apb, heb, cin);
  k6_scan2<<<Bn * Kn * NCH, 192, 0, stream>>>(ut, dblp, dt_w, dt_b, A_logs, Ds,
                                              cin, yacc);
  k7_outproj<<<512, 256, 0, stream>>>(yacc, onorm_g, onorm_b, out_proj, x, zt);
  k8_mfma<<<512, 256, 0, stream>>>(zt, norm2_g, norm2_b, w1b, fc1_b, w2b,
                                   fc2_b, x, out);
}